// Round 3
// baseline (7962.495 us; speedup 1.0000x reference)
//
#include <hip/hip_runtime.h>

typedef __attribute__((ext_vector_type(8))) short short8;
typedef __attribute__((ext_vector_type(4))) float f32x4;

#define MFMA(a,b,c) __builtin_amdgcn_mfma_f32_16x16x32_bf16(a,b,c,0,0,0)

// Problem dims
#define S_LEN 128
#define IN_D  8
#define HID   512
#define NL    3
#define HSTR  536   // bf16 h row stride (shorts); b128 reads spread across all quad-bank groups

// ws layout (bytes)
#define OFF_WHH 0                      // [3][32][16][3][64][8] bf16 = 4,718,592
#define OFF_WIH (4718592)              // [3][32][3][64][8] bf16    =   294,912

__device__ __forceinline__ unsigned short f2bf(float f){
  unsigned u = __float_as_uint(f);
  u += 0x7FFFu + ((u >> 16) & 1u);     // round-to-nearest-even
  return (unsigned short)(u >> 16);
}

// Pack Whh [3][1536][512] f32 -> bf16 B-fragments, gate-interleaved per kk:
// dst chunk gid = (((l*32+nt)*16+kk)*3+g)*64+lane ; holds Whh[l][g*512+nt*16+(lane&15)][kk*32+(lane>>4)*8 + j]
__global__ void prep_whh(const float* __restrict__ Whh, unsigned short* __restrict__ Wp){
  int gid = blockIdx.x * 256 + threadIdx.x;     // 294912 total
  int lane = gid & 63;
  int r = gid >> 6;
  int g  = r % 3;  r /= 3;
  int kk = r & 15; r >>= 4;
  int nt = r & 31;
  int l  = r >> 5;
  int n  = g * 512 + nt * 16 + (lane & 15);
  int k0 = kk * 32 + (lane >> 4) * 8;
  const float* src = Whh + ((size_t)l * 1536 + n) * 512 + k0;
  unsigned short t[8];
#pragma unroll
  for (int j = 0; j < 8; ++j) t[j] = f2bf(src[j]);
  uint4 v;
  v.x = t[0] | ((unsigned)t[1] << 16);
  v.y = t[2] | ((unsigned)t[3] << 16);
  v.z = t[4] | ((unsigned)t[5] << 16);
  v.w = t[6] | ((unsigned)t[7] << 16);
  *(uint4*)(Wp + (size_t)gid * 8) = v;
}

// Pack Wih [3][1536][8] -> zero-padded (K=8 of 32) B-fragments, gate-interleaved:
// dst chunk gid = ((l*32+nt)*3+g)*64+lane
__global__ void prep_wih(const float* __restrict__ Wih, unsigned short* __restrict__ Wip){
  int gid = blockIdx.x * 256 + threadIdx.x;     // 18432 total
  int lane = gid & 63;
  int r = gid >> 6;
  int g  = r % 3;  r /= 3;
  int nt = r & 31;
  int l  = r >> 5;
  unsigned short t[8] = {0,0,0,0,0,0,0,0};
  if ((lane >> 4) == 0){
    int n = g * 512 + nt * 16 + (lane & 15);
    const float* src = Wih + ((size_t)l * 1536 + n) * 8;
#pragma unroll
    for (int j = 0; j < 8; ++j) t[j] = f2bf(src[j]);
  }
  uint4 v;
  v.x = t[0] | ((unsigned)t[1] << 16);
  v.y = t[2] | ((unsigned)t[3] << 16);
  v.z = t[4] | ((unsigned)t[5] << 16);
  v.w = t[6] | ((unsigned)t[7] << 16);
  *(uint4*)(Wip + (size_t)gid * 8) = v;
}

// Main: 128 blocks x 1024 threads (16 waves, 4/SIMD, 1 block/CU).
// fp32 h master in registers; bf16 h double-buffered in LDS.
// Manual 2-deep register prefetch pipeline for weight (global) and A (LDS) fragments.
__global__ __launch_bounds__(1024, 4) void gru_main(
    const float* __restrict__ x,
    const unsigned short* __restrict__ Wp,
    const unsigned short* __restrict__ Wip,
    const float* __restrict__ bih,
    const float* __restrict__ bhh,
    float* __restrict__ out)
{
  __shared__ __align__(16) unsigned short hB[2][32 * HSTR];  // bf16 h, double buffer
  __shared__ __align__(16) unsigned short xpack[2][1024];    // x_t A-frags, t-parity buffers
  __shared__ float sBrz[3 * 1024];                           // bih+bhh for r,z
  __shared__ float sBni[3 * 512];                            // bih (n)
  __shared__ float sBnh[3 * 512];                            // bhh (n)

  const int tid  = threadIdx.x;
  const int wv   = tid >> 6;
  const int lane = tid & 63;
  const int l15  = lane & 15;
  const int l4   = lane >> 4;
  const int b0   = blockIdx.x * 32;

  for (int i = tid; i < 32 * HSTR; i += 1024){ hB[0][i] = 0; hB[1][i] = 0; }
  for (int i = tid; i < 3072; i += 1024){
    int l = i >> 10, c = i & 1023;
    sBrz[i] = bih[l * 1536 + c] + bhh[l * 1536 + c];
  }
  for (int i = tid; i < 1536; i += 1024){
    int l = i >> 9, c = i & 511;
    sBni[i] = bih[l * 1536 + 1024 + c];
    sBnh[i] = bhh[l * 1536 + 1024 + c];
  }

  // fp32 h master in registers: [p][m][q] -> batch row m*16+l4*4+q, col wv*32+p*16+l15
  float hreg[2][2][4];
#pragma unroll
  for (int p = 0; p < 2; ++p)
#pragma unroll
    for (int m = 0; m < 2; ++m)
#pragma unroll
      for (int q = 0; q < 4; ++q) hreg[p][m][q] = 0.f;

  // xpack writer mapping: tid = (m*64+lane)*8 + j
  const int xm = tid >> 9, xl = (tid >> 3) & 63, xj = tid & 7;
  const size_t xbase = ((size_t)(b0 + xm * 16 + (xl & 15))) * (S_LEN * IN_D) + xj;
  const int xvalid = (xl < 16);

  const int aoff0 = l15 * HSTR + l4 * 8;          // A-frag m=0 (rows 0..15), shorts
  const int aoff1 = aoff0 + 16 * HSTR;            // A-frag m=1 (rows 16..31)

  int cur = 0;
#pragma unroll 1
  for (int t = 0; t < S_LEN; ++t){
    { // stage x_t fragment into parity buffer
      float xv = xvalid ? x[xbase + (size_t)t * IN_D] : 0.f;
      xpack[t & 1][tid] = f2bf(xv);
    }
    const unsigned short* xp = &xpack[t & 1][0];

#pragma unroll 1
    for (int l = 0; l < NL; ++l){
      __syncthreads();   // prev layer's hB writes + this t's xpack visible
      const unsigned short* hbc = hB[cur];
      unsigned short*       hbn = hB[cur ^ 1];
#pragma unroll
      for (int p = 0; p < 2; ++p){
        const int cb  = wv * 32 + p * 16;        // output column base (0..511)
        const int ntc = (wv << 1) | p;           // col-tile 0..31
        const int col = cb + l15;

        // fragment pointers (gate-interleaved packing: +512/+1024 shorts per gate, +1536/kk)
        const unsigned short* wkl = Wp  + ((size_t)(((l * 32 + ntc) * 16) * 3) * 64 + lane) * 8;
        const unsigned short* wil = Wip + ((size_t)((l * 32 + ntc) * 3) * 64 + lane) * 8;
#define WLD(kk,g) (*(const short8*)(wkl + (kk) * 1536 + (g) * 512))
#define ILD(g)    (*(const short8*)(wil + (g) * 512))
#define ALD0(kk)  (*(const short8*)(hbc + aoff0 + (kk) * 32))
#define ALD1(kk)  (*(const short8*)(hbc + aoff1 + (kk) * 32))

        // issue gi loads + 2-deep prefetch before anything waits
        short8 ax0 = *(const short8*)(xp + lane * 8);
        short8 ax1 = *(const short8*)(xp + 512 + lane * 8);
        short8 iR = ILD(0), iZ = ILD(1), iN = ILD(2);
        short8 pa0[2], pa1[2], pR[2], pZ[2], pN[2];
        pa0[0] = ALD0(0); pa1[0] = ALD1(0); pR[0] = WLD(0,0); pZ[0] = WLD(0,1); pN[0] = WLD(0,2);
        pa0[1] = ALD0(1); pa1[1] = ALD1(1); pR[1] = WLD(1,0); pZ[1] = WLD(1,1); pN[1] = WLD(1,2);

        const float vR  = sBrz[l * 1024 + col];
        const float vZ  = sBrz[l * 1024 + 512 + col];
        const float vNi = sBni[l * 512 + col];
        const float vNh = sBnh[l * 512 + col];
        f32x4 accR0 = {vR,vR,vR,vR},     accR1 = {vR,vR,vR,vR};
        f32x4 accZ0 = {vZ,vZ,vZ,vZ},     accZ1 = {vZ,vZ,vZ,vZ};
        f32x4 accN0 = {vNh,vNh,vNh,vNh}, accN1 = {vNh,vNh,vNh,vNh};
        f32x4 giN0  = {vNi,vNi,vNi,vNi}, giN1  = {vNi,vNi,vNi,vNi};

        // gi = x_t @ Wih^T (zero-padded K=8 fragments)
        accR0 = MFMA(ax0, iR, accR0);  accR1 = MFMA(ax1, iR, accR1);
        accZ0 = MFMA(ax0, iZ, accZ0);  accZ1 = MFMA(ax1, iZ, accZ1);
        giN0  = MFMA(ax0, iN, giN0);   giN1  = MFMA(ax1, iN, giN1);

        // K loop with rotating 2-slot register pipeline (static indices via full unroll)
#pragma unroll
        for (int kk = 0; kk < 16; ++kk){
          const int c = kk & 1;
          short8 a0 = pa0[c], a1 = pa1[c];
          short8 bR = pR[c],  bZ = pZ[c],  bN = pN[c];
          if (kk < 14){
            pa0[c] = ALD0(kk + 2); pa1[c] = ALD1(kk + 2);
            pR[c]  = WLD(kk + 2, 0); pZ[c] = WLD(kk + 2, 1); pN[c] = WLD(kk + 2, 2);
          }
          accR0 = MFMA(a0, bR, accR0);  accR1 = MFMA(a1, bR, accR1);
          accZ0 = MFMA(a0, bZ, accZ0);  accZ1 = MFMA(a1, bZ, accZ1);
          accN0 = MFMA(a0, bN, accN0);  accN1 = MFMA(a1, bN, accN1);
        }
#undef WLD
#undef ILD
#undef ALD0
#undef ALD1

        // gates: registers only; packed u32 LDS writes (lane-pair exchange via shfl_xor)
#pragma unroll
        for (int m = 0; m < 2; ++m){
          f32x4 aR  = m ? accR1 : accR0;
          f32x4 aZ  = m ? accZ1 : accZ0;
          f32x4 aN4 = m ? accN1 : accN0;
          f32x4 gN  = m ? giN1  : giN0;
#pragma unroll
          for (int q = 0; q < 4; ++q){
            int b = m * 16 + l4 * 4 + q;           // batch row within tile
            float r  = 1.f / (1.f + __expf(-aR[q]));
            float z  = 1.f / (1.f + __expf(-aZ[q]));
            float aN = gN[q] + r * aN4[q];
            float n  = 1.f - 2.f / (1.f + __expf(2.f * aN));
            float hn = n + z * (hreg[p][m][q] - n);  // (1-z)*n + z*h
            hreg[p][m][q] = hn;
            unsigned bf = f2bf(hn);
            unsigned pb = (unsigned)__shfl_xor((int)bf, 1);
            if (!(l15 & 1))
              *(unsigned*)(hbn + b * HSTR + col) = bf | (pb << 16);
          }
        }
      }
      cur ^= 1;
    }
  }

  // epilogue: h master already in registers
#pragma unroll
  for (int p = 0; p < 2; ++p)
#pragma unroll
    for (int m = 0; m < 2; ++m)
#pragma unroll
      for (int q = 0; q < 4; ++q){
        int b   = m * 16 + l4 * 4 + q;
        int col = wv * 32 + p * 16 + l15;
        out[((size_t)(b0 + b)) * 512 + col] = hreg[p][m][q];
      }
}

extern "C" void kernel_launch(void* const* d_in, const int* in_sizes, int n_in,
                              void* d_out, int out_size, void* d_ws, size_t ws_size,
                              hipStream_t stream){
  const float* x   = (const float*)d_in[0];
  const float* Wih = (const float*)d_in[1];
  const float* Whh = (const float*)d_in[2];
  const float* bih = (const float*)d_in[3];
  const float* bhh = (const float*)d_in[4];

  unsigned char* ws = (unsigned char*)d_ws;
  unsigned short* Wp  = (unsigned short*)(ws + OFF_WHH);
  unsigned short* Wip = (unsigned short*)(ws + OFF_WIH);

  prep_whh <<<1152, 256, 0, stream>>>(Whh, Wp);
  prep_wih <<<  72, 256, 0, stream>>>(Wih, Wip);
  gru_main <<< 128, 1024, 0, stream>>>(x, Wp, Wip, bih, bhh, (float*)d_out);
}

// Round 4
// 4775.828 us; speedup vs baseline: 1.6672x; 1.6672x over previous
//
#include <hip/hip_runtime.h>

typedef __attribute__((ext_vector_type(8))) short short8;
typedef __attribute__((ext_vector_type(4))) float f32x4;

#define MFMA(a,b,c) __builtin_amdgcn_mfma_f32_16x16x32_bf16(a,b,c,0,0,0)

// Problem dims
#define S_LEN 128
#define IN_D  8
#define HID   512
#define NL    3
#define HSTR  536   // bf16 h row stride (shorts)

// ws layout (bytes)
#define OFF_WHH  0                       // [3][32][16][3][64][8] bf16 = 4,718,592
#define OFF_WIH  (4718592)               // [3][32][3][64][8] bf16    =   294,912
#define OFF_FLAG (4718592 + 294912)      // 256 * int                 =     1,024
#define OFF_XCHG (OFF_FLAG + 1024)       // 256 blk * 2 buf * 16 KB   = 8,388,608

__device__ __forceinline__ unsigned short f2bf(float f){
  unsigned u = __float_as_uint(f);
  u += 0x7FFFu + ((u >> 16) & 1u);     // round-to-nearest-even
  return (unsigned short)(u >> 16);
}

// Pack Whh [3][1536][512] f32 -> bf16 B-fragments, gate-interleaved per kk:
// dst chunk gid = (((l*32+nt)*16+kk)*3+g)*64+lane ; holds Whh[l][g*512+nt*16+(lane&15)][kk*32+(lane>>4)*8+j]
__global__ void prep_whh(const float* __restrict__ Whh, unsigned short* __restrict__ Wp){
  int gid = blockIdx.x * 256 + threadIdx.x;     // 294912 total
  int lane = gid & 63;
  int r = gid >> 6;
  int g  = r % 3;  r /= 3;
  int kk = r & 15; r >>= 4;
  int nt = r & 31;
  int l  = r >> 5;
  int n  = g * 512 + nt * 16 + (lane & 15);
  int k0 = kk * 32 + (lane >> 4) * 8;
  const float* src = Whh + ((size_t)l * 1536 + n) * 512 + k0;
  unsigned short t[8];
#pragma unroll
  for (int j = 0; j < 8; ++j) t[j] = f2bf(src[j]);
  uint4 v;
  v.x = t[0] | ((unsigned)t[1] << 16);
  v.y = t[2] | ((unsigned)t[3] << 16);
  v.z = t[4] | ((unsigned)t[5] << 16);
  v.w = t[6] | ((unsigned)t[7] << 16);
  *(uint4*)(Wp + (size_t)gid * 8) = v;
}

// Pack Wih [3][1536][8] -> zero-padded (K=8 of 32) B-fragments, gate-interleaved:
// dst chunk gid = ((l*32+nt)*3+g)*64+lane
__global__ void prep_wih(const float* __restrict__ Wih, unsigned short* __restrict__ Wip){
  int gid = blockIdx.x * 256 + threadIdx.x;     // 18432 total
  int lane = gid & 63;
  int r = gid >> 6;
  int g  = r % 3;  r /= 3;
  int nt = r & 31;
  int l  = r >> 5;
  unsigned short t[8] = {0,0,0,0,0,0,0,0};
  if ((lane >> 4) == 0){
    int n = g * 512 + nt * 16 + (lane & 15);
    const float* src = Wih + ((size_t)l * 1536 + n) * 8;
#pragma unroll
    for (int j = 0; j < 8; ++j) t[j] = f2bf(src[j]);
  }
  uint4 v;
  v.x = t[0] | ((unsigned)t[1] << 16);
  v.y = t[2] | ((unsigned)t[3] << 16);
  v.z = t[4] | ((unsigned)t[5] << 16);
  v.w = t[6] | ((unsigned)t[7] << 16);
  *(uint4*)(Wip + (size_t)gid * 8) = v;
}

// Main: 256 blocks x 1024 threads, 1 block/CU (all CUs active).
// Pair (bid, bid^4) shares batch rows [b0,b0+32); each computes 256 of 512 cols.
// half = (bid>>2)&1 aligns halves with XCDs (bid%8): per-XCD weight slice 2.36 MB -> L2-resident.
// h fp32 master in registers; bf16 h (full 512 cols) double-buffered in LDS.
// Per cell-layer: compute own half -> write LDS + coherent mailbox -> flag -> copy partner half.
__global__ __launch_bounds__(1024) __attribute__((amdgpu_waves_per_eu(4, 4)))
void gru_main(
    const float* __restrict__ x,
    const unsigned short* __restrict__ Wp,
    const unsigned short* __restrict__ Wip,
    const float* __restrict__ bih,
    const float* __restrict__ bhh,
    float* __restrict__ out,
    int* __restrict__ flags,
    unsigned int* __restrict__ xchg)
{
  __shared__ __align__(16) unsigned short hB[2][32 * HSTR];  // bf16 h, double buffer (full width)
  __shared__ __align__(16) unsigned short xpack[2][1024];    // x_t A-frags, t-parity buffers

  const int tid  = threadIdx.x;
  const int wv   = tid >> 6;
  const int lane = tid & 63;
  const int l15  = lane & 15;
  const int l4   = lane >> 4;

  const int bid     = blockIdx.x;
  const int bgroup  = ((bid >> 3) << 2) | (bid & 3);   // [0,128)
  const int half    = (bid >> 2) & 1;
  const int partner = bid ^ 4;
  const int b0      = bgroup * 32;
  const int cb      = half * 256 + wv * 16;            // this wave's column base
  const int ntc     = half * 16 + wv;                  // global 16-col tile index
  const int col     = cb + l15;
  const int pcb0    = (1 - half) * 256;                // partner's column base

  unsigned int* xown = xchg + (size_t)bid * 8192;      // 2 bufs x 4096 u32
  unsigned int* xpar = xchg + (size_t)partner * 8192;

  for (int i = tid; i < 32 * HSTR; i += 1024){ hB[0][i] = 0; hB[1][i] = 0; }

  // fp32 h master in registers: [m][q] -> batch row m*16+l4*4+q, col
  float hreg[2][4];
#pragma unroll
  for (int m = 0; m < 2; ++m)
#pragma unroll
    for (int q = 0; q < 4; ++q) hreg[m][q] = 0.f;

  // xpack writer mapping: tid = (m*64+lane)*8 + j
  const int xm = tid >> 9, xl = (tid >> 3) & 63, xj = tid & 7;
  const size_t xbase = ((size_t)(b0 + xm * 16 + (xl & 15))) * (S_LEN * IN_D) + xj;
  const int xvalid = (xl < 16);

  const int aoff0 = l15 * HSTR + l4 * 8;          // A-frag m=0 (rows 0..15), shorts
  const int aoff1 = aoff0 + 16 * HSTR;            // A-frag m=1 (rows 16..31)

  const unsigned short* wklB = Wp  + ((size_t)(ntc * 48) * 64 + lane) * 8;      // + l*32*48*512
  const unsigned short* wilB = Wip + ((size_t)(ntc * 3) * 64 + lane) * 8;       // + l*32*3*512

  int cur = 0;
#pragma unroll 1
  for (int t = 0; t < S_LEN; ++t){
    { // stage x_t fragment into parity buffer
      float xv = xvalid ? x[xbase + (size_t)t * IN_D] : 0.f;
      xpack[t & 1][tid] = f2bf(xv);
    }
    const unsigned short* xp = &xpack[t & 1][0];

#pragma unroll 1
    for (int l = 0; l < NL; ++l){
      const int s = t * NL + l;
      const int last = (s == S_LEN * NL - 1);
      __syncthreads();   // hB[cur] complete (own writes + partner copy); xpack visible
      const unsigned short* hbc = hB[cur];
      unsigned short*       hbn = hB[cur ^ 1];

      // biases from global (L2-hot broadcast-ish loads)
      const float vR  = bih[l * 1536 + col]        + bhh[l * 1536 + col];
      const float vZ  = bih[l * 1536 + 512 + col]  + bhh[l * 1536 + 512 + col];
      const float vNi = bih[l * 1536 + 1024 + col];
      const float vNh = bhh[l * 1536 + 1024 + col];
      f32x4 accR0 = {vR,vR,vR,vR},     accR1 = {vR,vR,vR,vR};
      f32x4 accZ0 = {vZ,vZ,vZ,vZ},     accZ1 = {vZ,vZ,vZ,vZ};
      f32x4 accN0 = {vNh,vNh,vNh,vNh}, accN1 = {vNh,vNh,vNh,vNh};
      f32x4 giN0  = {vNi,vNi,vNi,vNi}, giN1  = {vNi,vNi,vNi,vNi};

      // gi = x_t @ Wih^T (zero-padded K=8 fragments)
      {
        short8 ax0 = *(const short8*)(xp + lane * 8);
        short8 ax1 = *(const short8*)(xp + 512 + lane * 8);
        const unsigned short* wil = wilB + (size_t)l * 32 * 3 * 512;
        short8 iR = *(const short8*)(wil);
        short8 iZ = *(const short8*)(wil + 512);
        short8 iN = *(const short8*)(wil + 1024);
        accR0 = MFMA(ax0, iR, accR0);  accR1 = MFMA(ax1, iR, accR1);
        accZ0 = MFMA(ax0, iZ, accZ0);  accZ1 = MFMA(ax1, iZ, accZ1);
        giN0  = MFMA(ax0, iN, giN0);   giN1  = MFMA(ax1, iN, giN1);
      }

      // K loop: gh = h @ Whh^T, weights L2-resident slice
      const unsigned short* wkl = wklB + (size_t)l * 32 * 48 * 512;
#pragma unroll
      for (int kk = 0; kk < 16; ++kk){
        short8 a0 = *(const short8*)(hbc + aoff0 + kk * 32);
        short8 a1 = *(const short8*)(hbc + aoff1 + kk * 32);
        const unsigned short* w = wkl + kk * 1536;
        short8 bR = *(const short8*)(w);
        short8 bZ = *(const short8*)(w + 512);
        short8 bN = *(const short8*)(w + 1024);
        accR0 = MFMA(a0, bR, accR0);  accR1 = MFMA(a1, bR, accR1);
        accZ0 = MFMA(a0, bZ, accZ0);  accZ1 = MFMA(a1, bZ, accZ1);
        accN0 = MFMA(a0, bN, accN0);  accN1 = MFMA(a1, bN, accN1);
      }

      // gates; write own half to LDS next-buffer + coherent mailbox
      unsigned int* xob = xown + (s & 1) * 4096;
#pragma unroll
      for (int m = 0; m < 2; ++m){
        f32x4 aR  = m ? accR1 : accR0;
        f32x4 aZ  = m ? accZ1 : accZ0;
        f32x4 aN4 = m ? accN1 : accN0;
        f32x4 gN  = m ? giN1  : giN0;
#pragma unroll
        for (int q = 0; q < 4; ++q){
          int b = m * 16 + l4 * 4 + q;           // batch row within tile
          float r  = 1.f / (1.f + __expf(-aR[q]));
          float z  = 1.f / (1.f + __expf(-aZ[q]));
          float aN = gN[q] + r * aN4[q];
          float n  = 1.f - 2.f / (1.f + __expf(2.f * aN));
          float hn = n + z * (hreg[m][q] - n);   // (1-z)*n + z*h
          hreg[m][q] = hn;
          unsigned bf = f2bf(hn);
          unsigned pb = (unsigned)__shfl_xor((int)bf, 1);
          if (!(l15 & 1)){
            unsigned pk = bf | (pb << 16);
            *(unsigned*)(hbn + b * HSTR + col) = pk;
            if (!last){
              int lc = wv * 16 + l15;            // local col 0..255 (even)
              __hip_atomic_store(xob + (b * 128 + (lc >> 1)), pk,
                                 __ATOMIC_RELAXED, __HIP_MEMORY_SCOPE_AGENT);
            }
          }
        }
      }

      if (!last){
        asm volatile("s_waitcnt vmcnt(0)" ::: "memory");   // mailbox stores complete (coherent point)
        __syncthreads();                                   // all waves' stores drained
        if (tid == 0){
          __hip_atomic_store(&flags[bid], s + 1, __ATOMIC_RELAXED, __HIP_MEMORY_SCOPE_AGENT);
          while (__hip_atomic_load(&flags[partner], __ATOMIC_RELAXED, __HIP_MEMORY_SCOPE_AGENT) < s + 1)
            __builtin_amdgcn_s_sleep(8);
        }
        __syncthreads();                                   // partner data ready
        // copy partner half into hB[cur^1] (coherent loads bypass L1/L2)
        const unsigned int* pxb = xpar + (s & 1) * 4096;
#pragma unroll
        for (int i = 0; i < 4; ++i){
          int f = i * 1024 + tid;                // u32 index: b*128 + colpair
          unsigned v = __hip_atomic_load(pxb + f, __ATOMIC_RELAXED, __HIP_MEMORY_SCOPE_AGENT);
          int row = f >> 7, cp = f & 127;
          *(unsigned*)(hbn + row * HSTR + pcb0 + cp * 2) = v;
        }
      }
      cur ^= 1;
    }
  }

  // epilogue: own half from registers (partner writes the other half)
#pragma unroll
  for (int m = 0; m < 2; ++m)
#pragma unroll
    for (int q = 0; q < 4; ++q){
      int b = m * 16 + l4 * 4 + q;
      out[((size_t)(b0 + b)) * 512 + col] = hreg[m][q];
    }
}

extern "C" void kernel_launch(void* const* d_in, const int* in_sizes, int n_in,
                              void* d_out, int out_size, void* d_ws, size_t ws_size,
                              hipStream_t stream){
  const float* x   = (const float*)d_in[0];
  const float* Wih = (const float*)d_in[1];
  const float* Whh = (const float*)d_in[2];
  const float* bih = (const float*)d_in[3];
  const float* bhh = (const float*)d_in[4];

  unsigned char* ws = (unsigned char*)d_ws;
  unsigned short* Wp   = (unsigned short*)(ws + OFF_WHH);
  unsigned short* Wip  = (unsigned short*)(ws + OFF_WIH);
  int*            flg  = (int*)(ws + OFF_FLAG);
  unsigned int*   xchg = (unsigned int*)(ws + OFF_XCHG);

  hipMemsetAsync(flg, 0, 256 * sizeof(int), stream);   // generation flags start at 0 every call
  prep_whh <<<1152, 256, 0, stream>>>(Whh, Wp);
  prep_wih <<<  72, 256, 0, stream>>>(Wih, Wip);
  gru_main <<< 256, 1024, 0, stream>>>(x, Wp, Wip, bih, bhh, (float*)d_out, flg, xchg);
}